// Round 5
// baseline (183.302 us; speedup 1.0000x reference)
//
#include <hip/hip_runtime.h>

#define N_ROWS 65536
#define DIM 256
#define K_EMB 1024

typedef short bf16x8 __attribute__((ext_vector_type(8)));
typedef unsigned short ushort8_t __attribute__((ext_vector_type(8)));
typedef float f32x4 __attribute__((ext_vector_type(4)));

__device__ static inline unsigned short f2bf(float f) {
    unsigned int u = __float_as_uint(f);
    return (unsigned short)((u + 0x7fffu + ((u >> 16) & 1u)) >> 16);   // RNE
}

__device__ static inline void async16(const void* g, void* l) {
    __builtin_amdgcn_global_load_lds(
        (const __attribute__((address_space(1))) void*)g,
        (__attribute__((address_space(3))) void*)l, 16, 0, 0);
}

// ---------------- Kernel B: emb -> bf16 + half-norms + zero accum ---------------
__global__ __launch_bounds__(256)
void emb_prep_kernel(const float* __restrict__ emb, unsigned short* __restrict__ eb,
                     float* __restrict__ hn, float* __restrict__ loss_accum) {
    if (blockIdx.x == 0 && threadIdx.x == 0) loss_accum[0] = 0.0f;
    int wave = (blockIdx.x * 256 + threadIdx.x) >> 6;   // 1024 waves, one per emb row
    int lane = threadIdx.x & 63;
    float4 v = reinterpret_cast<const float4*>(emb + (size_t)wave * DIM)[lane];
    float s = v.x * v.x + v.y * v.y + v.z * v.z + v.w * v.w;
    #pragma unroll
    for (int off = 32; off > 0; off >>= 1) s += __shfl_xor(s, off, 64);
    if (lane == 0) hn[wave] = 0.5f * s;
    ushort4 w = { f2bf(v.x), f2bf(v.y), f2bf(v.z), f2bf(v.w) };
    *reinterpret_cast<ushort4*>(eb + (size_t)wave * DIM + lane * 4) = w;
}

// ---------------- Kernel C: MFMA score GEMM + fused row-argmax -------------------
// Block: 256 rows x ALL 1024 cols. 4 waves x 64 rows (4 m-tiles), A (K=256) in
// registers (128 VGPRs), converted fp32->bf16 in-kernel during wave-local staging.
// B swept in 16 chunks of 64 cols, double-buffered global_load_lds, full staging.
// LDS: A regions [w*32K,(w+1)*32K) overlaid by B bufs [0,32K)+[32K,64K); hn @128K.
__global__ __launch_bounds__(256, 1)
void argmax_mfma_kernel(const float* __restrict__ x,
                        const unsigned short* __restrict__ eb,
                        const float* __restrict__ hn, int* __restrict__ out_idx) {
    __shared__ __align__(16) char smem[135168];
    float* hns = reinterpret_cast<float*>(smem + 131072);

    const int t    = threadIdx.x;
    const int w    = t >> 6, lane = t & 63;
    const int q    = lane >> 4, l15 = lane & 15;
    const int n0   = blockIdx.x * 256;

    #pragma unroll
    for (int i = 0; i < 4; ++i) hns[t + i * 256] = hn[t + i * 256];

    // ---- wave-local A staging: 64 rows x 256 d, fp32 -> bf16, swizzled packets --
    char* aRegion = smem + w * 32768;
    {
        const float* xw = x + (size_t)(n0 + w * 64) * DIM;
        #pragma unroll
        for (int i = 0; i < 32; ++i) {
            int p  = i * 64 + lane;            // 0..2047 packets
            int rw = p >> 5;                   // local row 0..63
            int j  = p & 31;                   // LDS packet slot
            int g  = (j & 24) | ((j ^ rw) & 7);  // global packet (XOR swizzle)
            const float4* src = reinterpret_cast<const float4*>(xw + (size_t)rw * DIM + g * 8);
            float4 a = src[0], b = src[1];
            ushort8_t v;
            v[0] = f2bf(a.x); v[1] = f2bf(a.y); v[2] = f2bf(a.z); v[3] = f2bf(a.w);
            v[4] = f2bf(b.x); v[5] = f2bf(b.y); v[6] = f2bf(b.z); v[7] = f2bf(b.w);
            *reinterpret_cast<ushort8_t*>(aRegion + p * 16) = v;
        }
    }
    // ---- A fragments to registers: 4 m-tiles x 8 k-steps (wave-local, no barrier)
    bf16x8 a[4][8];
    #pragma unroll
    for (int mt = 0; mt < 4; ++mt) {
        int rw = mt * 16 + l15;
        #pragma unroll
        for (int ks = 0; ks < 8; ++ks) {
            int pk = ks * 4 + q;
            int j  = (pk & 24) | ((pk ^ rw) & 7);
            a[mt][ks] = *reinterpret_cast<const bf16x8*>(aRegion + (rw * 32 + j) * 16);
        }
    }
    __syncthreads();   // all waves done with A regions; B buffers may overlay

    // ---- B staging constants: 8 issues/thread cover ALL 2048 packets/chunk ------
    const unsigned short* egp[8];
    int dstOff[8];
    #pragma unroll
    for (int i = 0; i < 8; ++i) {
        int p   = i * 256 + t;                 // 0..2047
        int col = p >> 5;                      // 0..63
        int j   = p & 31;
        int g   = (j & 24) | ((j ^ col) & 7);
        egp[i]    = eb + (size_t)col * DIM + g * 8;
        dstOff[i] = p * 16;
    }
    // B-frag offsets: col stride 512 B; swizzle depends only on l15 (col&7==l15&7)
    int jsw[8];
    #pragma unroll
    for (int ks = 0; ks < 8; ++ks) {
        int pk = ks * 4 + q;
        jsw[ks] = ((pk & 24) | ((pk ^ l15) & 7)) * 16;
    }
    int cbase[4];
    #pragma unroll
    for (int nt = 0; nt < 4; ++nt) cbase[nt] = (nt * 16 + l15) * 512;

    float best[16];
    int   bidx[16];
    #pragma unroll
    for (int i = 0; i < 16; ++i) { best[i] = -1e30f; bidx[i] = 0; }

    // prefetch chunk 0 -> buf0
    #pragma unroll
    for (int i = 0; i < 8; ++i) async16(egp[i], smem + dstOff[i]);

    for (int c = 0; c < 16; ++c) {
        __syncthreads();   // chunk c staged (vmcnt drained); other buf free
        const char* buf = smem + (c & 1) * 32768;
        if (c < 15) {
            char* nb = smem + ((c + 1) & 1) * 32768;
            #pragma unroll
            for (int i = 0; i < 8; ++i)
                async16(egp[i] + (size_t)(c + 1) * 64 * DIM, nb + dstOff[i]);
        }
        f32x4 acc[4][4];
        #pragma unroll
        for (int nt = 0; nt < 4; ++nt) {
            float h = -hns[c * 64 + nt * 16 + l15];
            f32x4 in4 = {h, h, h, h};
            #pragma unroll
            for (int mt = 0; mt < 4; ++mt) acc[mt][nt] = in4;
        }
        #pragma unroll
        for (int ks = 0; ks < 8; ++ks) {
            bf16x8 b[4];
            #pragma unroll
            for (int nt = 0; nt < 4; ++nt)
                b[nt] = *reinterpret_cast<const bf16x8*>(buf + cbase[nt] + jsw[ks]);
            #pragma unroll
            for (int mt = 0; mt < 4; ++mt)
                #pragma unroll
                for (int nt = 0; nt < 4; ++nt)
                    acc[mt][nt] = __builtin_amdgcn_mfma_f32_16x16x32_bf16(
                        a[mt][ks], b[nt], acc[mt][nt], 0, 0, 0);
        }
        // epilogue: scores include -0.5||e||^2; cols ascend per lane -> strict >
        #pragma unroll
        for (int nt = 0; nt < 4; ++nt) {
            int k = c * 64 + nt * 16 + l15;
            #pragma unroll
            for (int mt = 0; mt < 4; ++mt)
                #pragma unroll
                for (int r = 0; r < 4; ++r) {
                    float sc = acc[mt][nt][r];
                    int slot = mt * 4 + r;
                    if (sc > best[slot]) { best[slot] = sc; bidx[slot] = k; }
                }
        }
    }

    // butterfly argmax across the 16 l15 lanes (lowest index wins ties)
    #pragma unroll
    for (int slot = 0; slot < 16; ++slot) {
        float bs = best[slot]; int bi = bidx[slot];
        #pragma unroll
        for (int off = 8; off >= 1; off >>= 1) {
            float os = __shfl_xor(bs, off, 64);
            int   oi = __shfl_xor(bi, off, 64);
            if (os > bs || (os == bs && oi < bi)) { bs = os; bi = oi; }
        }
        bidx[slot] = bi;
    }
    if (l15 == 0) {
        #pragma unroll
        for (int mt = 0; mt < 4; ++mt) {
            int4 v = { bidx[mt * 4 + 0], bidx[mt * 4 + 1], bidx[mt * 4 + 2], bidx[mt * 4 + 3] };
            *reinterpret_cast<int4*>(out_idx + n0 + w * 64 + mt * 16 + q * 4) = v;
        }
    }
}

// ---------------- Kernel D: gather quantized + loss (8 rows/wave) ----------------
#define GL_BLOCKS 2048
__global__ __launch_bounds__(256)
void gather_loss_kernel(const float* __restrict__ x, const float* __restrict__ emb,
                        const int* __restrict__ idx, float* __restrict__ out,
                        float* __restrict__ loss_accum) {
    int wv   = blockIdx.x * 4 + (threadIdx.x >> 6);   // 8192 waves
    int lane = threadIdx.x & 63;
    int r0   = wv * 8;                                 // 8 rows per wave
    float s  = 0.0f;
    #pragma unroll
    for (int i = 0; i < 8; ++i) {
        int n = r0 + i;
        int k = idx[n];
        float4 qv = *reinterpret_cast<const float4*>(emb + (size_t)k * DIM + lane * 4);
        float4 xv = *reinterpret_cast<const float4*>(x + (size_t)n * DIM + lane * 4);
        *reinterpret_cast<float4*>(out + (size_t)n * DIM + lane * 4) = qv;
        float dx = qv.x - xv.x, dy = qv.y - xv.y, dz = qv.z - xv.z, dw = qv.w - xv.w;
        s += dx * dx + dy * dy + dz * dz + dw * dw;
    }
    #pragma unroll
    for (int off = 32; off > 0; off >>= 1) s += __shfl_xor(s, off, 64);
    __shared__ float partial[4];
    int lid = threadIdx.x & 63, wvl = threadIdx.x >> 6;
    if (lid == 0) partial[wvl] = s;
    __syncthreads();
    if (threadIdx.x == 0)
        atomicAdd(loss_accum, partial[0] + partial[1] + partial[2] + partial[3]);
}

// ---------------- Kernel E: finalize loss ---------------------------------------
__global__ void finalize_kernel(const float* __restrict__ loss_accum,
                                float* __restrict__ out_loss) {
    if (threadIdx.x == 0)
        out_loss[0] = 1.25f * loss_accum[0] / 16777216.0f;
}

extern "C" void kernel_launch(void* const* d_in, const int* in_sizes, int n_in,
                              void* d_out, int out_size, void* d_ws, size_t ws_size,
                              hipStream_t stream) {
    const float* x   = reinterpret_cast<const float*>(d_in[0]);
    const float* emb = reinterpret_cast<const float*>(d_in[1]);
    float* out       = reinterpret_cast<float*>(d_out);
    float* loss_out  = out + (size_t)N_ROWS * DIM;

    char* ws = reinterpret_cast<char*>(d_ws);
    float*          loss_accum = reinterpret_cast<float*>(ws);                 // 256 B
    float*          hn         = reinterpret_cast<float*>(ws + 4096);          // 4 KB
    int*            idx        = reinterpret_cast<int*>(ws + 8192);            // 256 KB
    unsigned short* eb         = reinterpret_cast<unsigned short*>(ws + 524288);    // 512 KB

    emb_prep_kernel<<<K_EMB / 4, 256, 0, stream>>>(emb, eb, hn, loss_accum);
    argmax_mfma_kernel<<<N_ROWS / 256, 256, 0, stream>>>(x, eb, hn, idx);
    gather_loss_kernel<<<GL_BLOCKS, 256, 0, stream>>>(x, emb, idx, out, loss_accum);
    finalize_kernel<<<1, 64, 0, stream>>>(loss_accum, loss_out);
}